// Round 1
// baseline (403.482 us; speedup 1.0000x reference)
//
#include <hip/hip_runtime.h>

// Fused attention block: B=1, T=2048, D=2048, NH=16, NKV=4, HD=128, REP=4
// Pipeline:
//  prep:    xb = bf16(x); xmb = bf16((1-g)x + g*skip); colbias/hscale
//  convw:   wq/wk/wv/wproj fp32 -> bf16 (wk,wv contiguous => one kv GEMM N=1024)
//  gemm:    qraw = xb @ wq^T                (fp32 out)
//  gemm:    kvraw = xmb @ [wk;wv]^T + colbias
//  postqk:  rmsnorm + rope -> qb[h][t][128], kb[h][t][128] (bf16)
//  transv:  vT[h*128+d][t] bf16
//  flash:   causal GQA flash attention -> ao[t][2048] bf16
//  gemm:    out = ao @ wproj^T * ln_s       (fp32 out)

typedef float  f32x4 __attribute__((ext_vector_type(4)));
typedef short  s16x8 __attribute__((ext_vector_type(8)));
typedef unsigned short u16;

#define DEVI __device__ __forceinline__

DEVI u16 f2bf(float f) {
  union { float f; unsigned u; } c; c.f = f;
  unsigned u = c.u + 0x7fffu + ((c.u >> 16) & 1u);
  return (u16)(u >> 16);
}

DEVI void gl_lds16(const void* g, void* l) {
  __builtin_amdgcn_global_load_lds(
      (const __attribute__((address_space(1))) unsigned int*)g,
      (__attribute__((address_space(3))) unsigned int*)l, 16, 0, 0);
}

// ---------------- prep: x/xm conversion + misc constants -------------------
__global__ __launch_bounds__(256) void prep_kernel(
    const float* __restrict__ x, const float* __restrict__ skip,
    const float* __restrict__ ln_s, const float* __restrict__ v_bias,
    const float* __restrict__ qk_g, u16* __restrict__ xb, u16* __restrict__ xmb,
    float* __restrict__ colbias, float* __restrict__ hscale) {
  float g = 1.0f / (1.0f + __expf(-ln_s[0] * 0.1f));
  int i = (blockIdx.x * 256 + threadIdx.x) * 4;
  float4 xv = *(const float4*)(x + i);
  float4 sv = *(const float4*)(skip + i);
  ushort4 a, b;
  a.x = f2bf(xv.x); a.y = f2bf(xv.y); a.z = f2bf(xv.z); a.w = f2bf(xv.w);
  b.x = f2bf((1.f - g) * xv.x + g * sv.x);
  b.y = f2bf((1.f - g) * xv.y + g * sv.y);
  b.z = f2bf((1.f - g) * xv.z + g * sv.z);
  b.w = f2bf((1.f - g) * xv.w + g * sv.w);
  *(ushort4*)(xb + i) = a;
  *(ushort4*)(xmb + i) = b;
  if (blockIdx.x == 0) {
    int t = threadIdx.x;
    for (int k = t; k < 512; k += 256) {
      colbias[k] = 0.f;
      colbias[512 + k] = (1.f - g) * v_bias[k];
    }
    if (t < 16) { float gq = qk_g[t]; hscale[t] = gq * gq * 0.08838834764831845f; }
  }
}

// ---------------- weight conversion fp32->bf16 -----------------------------
__global__ __launch_bounds__(256) void convw_kernel(
    const float* __restrict__ wq, const float* __restrict__ wk,
    const float* __restrict__ wv, const float* __restrict__ wp,
    u16* __restrict__ wb) {
  size_t i = ((size_t)blockIdx.x * 256 + threadIdx.x) * 4;
  constexpr size_t M4 = 4u * 1024 * 1024, M1 = 1024 * 1024;
  const float* src;
  if (i < M4) src = wq + i;
  else if (i < M4 + M1) src = wk + (i - M4);
  else if (i < M4 + 2 * M1) src = wv + (i - M4 - M1);
  else src = wp + (i - M4 - 2 * M1);
  float4 v = *(const float4*)src;
  ushort4 o;
  o.x = f2bf(v.x); o.y = f2bf(v.y); o.z = f2bf(v.z); o.w = f2bf(v.w);
  *(ushort4*)(wb + i) = o;
}

// ---------------- NT GEMM: C(MxN) = A(MxK) * B(NxK)^T, bf16 in, fp32 out ---
// m97 structure: 128x128 tile, BK=32, 4 waves each 64x64, global_load_lds w=16
template <int BIAS, int SCALE>
__global__ __launch_bounds__(256) void gemm_nt(
    const u16* __restrict__ A, const u16* __restrict__ B, float* __restrict__ C,
    int M, int N, int K, const float* __restrict__ bias,
    const float* __restrict__ scale) {
  __shared__ u16 lA[128 * 32];
  __shared__ u16 lB[128 * 32];
  const int tid = threadIdx.x;
  const int lane = tid & 63, w = tid >> 6;
  const int m0 = blockIdx.y * 128, n0 = blockIdx.x * 128;
  const int mo = (w >> 1) * 64, no = (w & 1) * 64;
  const int r16 = lane & 15, q4 = lane >> 4;
  f32x4 acc[4][4] = {};

  for (int k0 = 0; k0 < K; k0 += 32) {
#pragma unroll
    for (int j = 0; j < 2; ++j) {
      int slot = j * 256 + tid;
      int row = slot >> 2, c8 = (slot & 3) * 8;
      gl_lds16(A + (size_t)(m0 + row) * K + k0 + c8, &lA[slot * 8]);
    }
#pragma unroll
    for (int j = 0; j < 2; ++j) {
      int slot = j * 256 + tid;
      int row = slot >> 2, c8 = (slot & 3) * 8;
      gl_lds16(B + (size_t)(n0 + row) * K + k0 + c8, &lB[slot * 8]);
    }
    __syncthreads();
    s16x8 af[4], bfr[4];
#pragma unroll
    for (int i = 0; i < 4; ++i)
      af[i] = *(const s16x8*)&lA[(mo + i * 16 + r16) * 32 + q4 * 8];
#pragma unroll
    for (int i = 0; i < 4; ++i)
      bfr[i] = *(const s16x8*)&lB[(no + i * 16 + r16) * 32 + q4 * 8];
#pragma unroll
    for (int mi = 0; mi < 4; ++mi)
#pragma unroll
      for (int ni = 0; ni < 4; ++ni)
        acc[mi][ni] = __builtin_amdgcn_mfma_f32_16x16x32_bf16(
            af[mi], bfr[ni], acc[mi][ni], 0, 0, 0);
    __syncthreads();
  }
  float sc = SCALE ? scale[0] : 1.0f;
#pragma unroll
  for (int mi = 0; mi < 4; ++mi) {
#pragma unroll
    for (int ni = 0; ni < 4; ++ni) {
      int col = n0 + no + ni * 16 + r16;
      float bv = BIAS ? bias[col] : 0.0f;
#pragma unroll
      for (int r = 0; r < 4; ++r) {
        int row = m0 + mo + mi * 16 + q4 * 4 + r;
        C[(size_t)row * N + col] = (acc[mi][ni][r] + bv) * sc;
      }
    }
  }
}

// ---------------- rmsnorm + rope for q and k -------------------------------
__global__ __launch_bounds__(256) void postqk_kernel(
    const float* __restrict__ qraw, const float* __restrict__ kvraw,
    u16* __restrict__ qb, u16* __restrict__ kb) {
  constexpr int T = 2048;
  const int lane = threadIdx.x & 63, w = threadIdx.x >> 6;
  int p = blockIdx.x * 4 + w;  // 0..20*T-1
  const float* src;
  u16* dst;
  int t;
  if (p < 16 * T) {
    int hh = p >> 11; t = p & 2047;
    src = qraw + (size_t)t * 2048 + hh * 128;
    dst = qb + ((size_t)hh * T + t) * 128;
  } else {
    p -= 16 * T;
    int hh = p >> 11; t = p & 2047;
    src = kvraw + (size_t)t * 1024 + hh * 128;
    dst = kb + ((size_t)hh * T + t) * 128;
  }
  float x1 = src[lane], x2 = src[lane + 64];
  float ss = x1 * x1 + x2 * x2;
  ss += __shfl_xor(ss, 1);  ss += __shfl_xor(ss, 2);  ss += __shfl_xor(ss, 4);
  ss += __shfl_xor(ss, 8);  ss += __shfl_xor(ss, 16); ss += __shfl_xor(ss, 32);
  float rn = rsqrtf(ss * (1.0f / 128.0f) + 1.1920929e-7f);
  // inv_freq = 10000^(-lane/64) ; ln(10000)/64 = 0.14391156831212787
  float fr = (float)t * expf((float)lane * -0.14391156831212787f);
  float c = cosf(fr), s = sinf(fr);
  float y1 = (x1 * c + x2 * s) * rn;   // x1*cos + x2*sin
  float y2 = (x2 * c - x1 * s) * rn;   // -x1*sin + x2*cos
  dst[lane] = f2bf(y1);
  dst[lane + 64] = f2bf(y2);
}

// ---------------- transpose v: vT[hd][t] = kvraw[t][512+hd] ----------------
__global__ __launch_bounds__(256) void transv_kernel(
    const float* __restrict__ kvraw, u16* __restrict__ vT) {
  constexpr int T = 2048;
  __shared__ float tile[32][33];
  int t0 = blockIdx.x * 32, hd0 = blockIdx.y * 32;
  int tx = threadIdx.x & 31, ty = threadIdx.x >> 5;  // ty 0..7
#pragma unroll
  for (int i = 0; i < 4; ++i) {
    int t = t0 + ty + i * 8;
    tile[ty + i * 8][tx] = kvraw[(size_t)t * 1024 + 512 + hd0 + tx];
  }
  __syncthreads();
#pragma unroll
  for (int i = 0; i < 4; ++i) {
    int hd = hd0 + ty + i * 8;
    vT[(size_t)hd * T + t0 + tx] = f2bf(tile[tx][ty + i * 8]);
  }
}

// ---------------- causal GQA flash attention -------------------------------
// grid: (32 qblocks reversed, 16 heads); 4 waves x 16 q-rows; KV tiles of 32
__global__ __launch_bounds__(256) void flash_kernel(
    const u16* __restrict__ qb, const u16* __restrict__ kb,
    const u16* __restrict__ vT, u16* __restrict__ out,
    const float* __restrict__ hscale) {
  constexpr int T = 2048;
  __shared__ u16 lK[32 * 128];   // [kv][d], XOR-swizzled: byte ^= (row&7)<<4
  __shared__ u16 lV[128 * 32];   // [d][kv], XOR-swizzled: byte ^= ((row>>1)&3)<<4
  __shared__ u16 lP[4][16 * 56]; // per-wave P, stride 56 elems (2-way banks)
  const int tid = threadIdx.x, lane = tid & 63, w = tid >> 6;
  const int h = blockIdx.y, hkv = h >> 2;
  const int q0 = (int)(gridDim.x - 1 - blockIdx.x) * 64;
  const int r16 = lane & 15, q4 = lane >> 4;

  s16x8 qf[4];
  {
    const u16* qp = qb + ((size_t)h * T + q0 + w * 16 + r16) * 128 + q4 * 8;
#pragma unroll
    for (int d = 0; d < 4; ++d) qf[d] = *(const s16x8*)(qp + d * 32);
  }
  const float sc = hscale[h];
  f32x4 O[8] = {};
  float m_[4], l_[4];
#pragma unroll
  for (int r = 0; r < 4; ++r) { m_[r] = -3.0e38f; l_[r] = 0.f; }
  const int qrow = q0 + w * 16 + q4 * 4;  // + r
  const int nt = (q0 + 64) / 32;

  for (int it = 0; it < nt; ++it) {
    const int t0 = it * 32;
#pragma unroll
    for (int j = 0; j < 2; ++j) {  // K tile: 32 rows x 256B
      int slot = j * 256 + tid;
      int row = slot >> 4;
      int cb = ((slot & 15) * 16) ^ ((row & 7) << 4);
      gl_lds16(kb + ((size_t)hkv * T + t0 + row) * 128 + (cb >> 1), &lK[slot * 8]);
    }
#pragma unroll
    for (int j = 0; j < 2; ++j) {  // V^T tile: 128 rows x 64B
      int slot = j * 256 + tid;
      int row = slot >> 2;
      int cb = ((slot & 3) * 16) ^ (((row >> 1) & 3) << 4);
      gl_lds16(vT + ((size_t)hkv * 128 + row) * T + t0 + (cb >> 1), &lV[slot * 8]);
    }
    __syncthreads();

    f32x4 s0 = {}, s1 = {};
#pragma unroll
    for (int d = 0; d < 4; ++d) {
      int cb = (q4 * 16 + d * 64) ^ ((r16 & 7) << 4);
      s16x8 kf = *(const s16x8*)&lK[r16 * 128 + (cb >> 1)];
      s0 = __builtin_amdgcn_mfma_f32_16x16x32_bf16(qf[d], kf, s0, 0, 0, 0);
    }
#pragma unroll
    for (int d = 0; d < 4; ++d) {
      int krow = 16 + r16;
      int cb = (q4 * 16 + d * 64) ^ ((krow & 7) << 4);
      s16x8 kf = *(const s16x8*)&lK[krow * 128 + (cb >> 1)];
      s1 = __builtin_amdgcn_mfma_f32_16x16x32_bf16(qf[d], kf, s1, 0, 0, 0);
    }
    float sv0[4], sv1[4];
#pragma unroll
    for (int r = 0; r < 4; ++r) {
      sv0[r] = (t0 + r16      <= qrow + r) ? s0[r] * sc : -3.0e38f;
      sv1[r] = (t0 + 16 + r16 <= qrow + r) ? s1[r] * sc : -3.0e38f;
    }
    float al[4];
#pragma unroll
    for (int r = 0; r < 4; ++r) {
      float t = fmaxf(sv0[r], sv1[r]);
      t = fmaxf(t, __shfl_xor(t, 1));
      t = fmaxf(t, __shfl_xor(t, 2));
      t = fmaxf(t, __shfl_xor(t, 4));
      t = fmaxf(t, __shfl_xor(t, 8));
      float mn = fmaxf(m_[r], t);
      al[r] = __expf(m_[r] - mn);
      m_[r] = mn;
    }
    u16* myP = &lP[w][0];
#pragma unroll
    for (int r = 0; r < 4; ++r) {
      float p0 = __expf(sv0[r] - m_[r]);
      float p1 = __expf(sv1[r] - m_[r]);
      int row = q4 * 4 + r;
      myP[row * 56 + r16] = f2bf(p0);
      myP[row * 56 + 16 + r16] = f2bf(p1);
      float s = p0 + p1;
      s += __shfl_xor(s, 1); s += __shfl_xor(s, 2);
      s += __shfl_xor(s, 4); s += __shfl_xor(s, 8);
      l_[r] = l_[r] * al[r] + s;
    }
#pragma unroll
    for (int dt = 0; dt < 8; ++dt)
#pragma unroll
      for (int r = 0; r < 4; ++r) O[dt][r] *= al[r];
    asm volatile("s_waitcnt lgkmcnt(0)" ::: "memory");
    s16x8 pf = *(const s16x8*)&myP[r16 * 56 + q4 * 8];
#pragma unroll
    for (int dt = 0; dt < 8; ++dt) {
      int vrow = dt * 16 + r16;
      int cb = (q4 * 16) ^ (((vrow >> 1) & 3) << 4);
      s16x8 vf = *(const s16x8*)&lV[vrow * 32 + (cb >> 1)];
      O[dt] = __builtin_amdgcn_mfma_f32_16x16x32_bf16(pf, vf, O[dt], 0, 0, 0);
    }
    __syncthreads();
  }
  float inv[4];
#pragma unroll
  for (int r = 0; r < 4; ++r) inv[r] = 1.0f / l_[r];
#pragma unroll
  for (int dt = 0; dt < 8; ++dt) {
#pragma unroll
    for (int r = 0; r < 4; ++r) {
      int row = qrow + r;
      int col = h * 128 + dt * 16 + r16;
      out[(size_t)row * 2048 + col] = f2bf(O[dt][r] * inv[r]);
    }
  }
}

// ---------------------------------------------------------------------------
extern "C" void kernel_launch(void* const* d_in, const int* in_sizes, int n_in,
                              void* d_out, int out_size, void* d_ws,
                              size_t ws_size, hipStream_t stream) {
  const float* x      = (const float*)d_in[0];
  const float* skip   = (const float*)d_in[1];
  const float* wq     = (const float*)d_in[2];
  const float* wk     = (const float*)d_in[3];
  const float* wv     = (const float*)d_in[4];
  const float* wp     = (const float*)d_in[5];
  const float* qk_g   = (const float*)d_in[6];
  const float* ln_s   = (const float*)d_in[7];
  const float* v_bias = (const float*)d_in[8];
  float* out = (float*)d_out;

  constexpr size_t MB = 1024 * 1024;
  char* ws = (char*)d_ws;
  u16*   wb    = (u16*)(ws);             // 10M bf16 = 20MB: wq|wk|wv|wp
  u16*   xb    = (u16*)(ws + 20 * MB);   // 8MB
  u16*   xmb   = (u16*)(ws + 28 * MB);   // 8MB
  float* qraw  = (float*)(ws + 36 * MB); // 16MB
  float* kvraw = (float*)(ws + 52 * MB); // 8MB
  u16*   qb    = (u16*)(ws + 60 * MB);   // 8MB
  u16*   kb    = (u16*)(ws + 68 * MB);   // 2MB
  u16*   vT    = (u16*)(ws + 70 * MB);   // 2MB
  u16*   ao    = (u16*)(ws + 72 * MB);   // 8MB
  float* colbias = (float*)(ws + 80 * MB);
  float* hscale  = (float*)(ws + 80 * MB + 4096);

  prep_kernel<<<4096, 256, 0, stream>>>(x, skip, ln_s, v_bias, qk_g, xb, xmb,
                                        colbias, hscale);
  convw_kernel<<<10240, 256, 0, stream>>>(wq, wk, wv, wp, wb);
  gemm_nt<0, 0><<<dim3(16, 16), 256, 0, stream>>>(xb, wb, qraw, 2048, 2048,
                                                  2048, nullptr, nullptr);
  gemm_nt<1, 0><<<dim3(8, 16), 256, 0, stream>>>(
      xmb, wb + 4 * MB, kvraw, 2048, 1024, 2048, colbias, nullptr);
  postqk_kernel<<<10240, 256, 0, stream>>>(qraw, kvraw, qb, kb);
  transv_kernel<<<dim3(64, 16), 256, 0, stream>>>(kvraw, vT);
  flash_kernel<<<dim3(32, 16), 256, 0, stream>>>(qb, kb, vT, ao, hscale);
  gemm_nt<0, 1><<<dim3(16, 16), 256, 0, stream>>>(
      ao, wb + 6 * MB, out, 2048, 2048, 2048, nullptr, ln_s);
}

// Round 5
// 354.712 us; speedup vs baseline: 1.1375x; 1.1375x over previous
//
#include <hip/hip_runtime.h>

// Fused attention block: B=1, T=2048, D=2048, NH=16, NKV=4, HD=128, REP=4
// Pipeline:
//  prep:    xb = bf16(x); xmb = bf16((1-g)x + g*skip); colbias
//  convw:   wq/wk/wv/wproj fp32 -> bf16 (wk,wv contiguous => one kv GEMM N=1024)
//  gemm:    qraw = xb @ wq^T                (fp32 out)
//  gemm:    kvraw = xmb @ [wk;wv]^T + colbias
//  postqk:  rmsnorm + rope -> qb (scaled by gain^2/sqrt(128)*log2e), kb (bf16)
//  transv:  vT[h*128+d][t] bf16
//  flash:   causal GQA flash attention (KVBLK=64, double-buffered) -> ao bf16
//  gemm:    out = ao @ wproj^T * ln_s       (fp32 out)

typedef float  f32x4 __attribute__((ext_vector_type(4)));
typedef short  s16x8 __attribute__((ext_vector_type(8)));
typedef unsigned short u16;

#define DEVI __device__ __forceinline__

DEVI u16 f2bf(float f) {
  union { float f; unsigned u; } c; c.f = f;
  unsigned u = c.u + 0x7fffu + ((c.u >> 16) & 1u);
  return (u16)(u >> 16);
}

DEVI void gl_lds16(const void* g, void* l) {
  __builtin_amdgcn_global_load_lds(
      (const __attribute__((address_space(1))) unsigned int*)g,
      (__attribute__((address_space(3))) unsigned int*)l, 16, 0, 0);
}

// ---------------- prep: x/xm conversion + misc constants -------------------
__global__ __launch_bounds__(256) void prep_kernel(
    const float* __restrict__ x, const float* __restrict__ skip,
    const float* __restrict__ ln_s, const float* __restrict__ v_bias,
    u16* __restrict__ xb, u16* __restrict__ xmb, float* __restrict__ colbias) {
  float g = 1.0f / (1.0f + __expf(-ln_s[0] * 0.1f));
  int i = (blockIdx.x * 256 + threadIdx.x) * 4;
  float4 xv = *(const float4*)(x + i);
  float4 sv = *(const float4*)(skip + i);
  ushort4 a, b;
  a.x = f2bf(xv.x); a.y = f2bf(xv.y); a.z = f2bf(xv.z); a.w = f2bf(xv.w);
  b.x = f2bf((1.f - g) * xv.x + g * sv.x);
  b.y = f2bf((1.f - g) * xv.y + g * sv.y);
  b.z = f2bf((1.f - g) * xv.z + g * sv.z);
  b.w = f2bf((1.f - g) * xv.w + g * sv.w);
  *(ushort4*)(xb + i) = a;
  *(ushort4*)(xmb + i) = b;
  if (blockIdx.x == 0) {
    int t = threadIdx.x;
    for (int k = t; k < 512; k += 256) {
      colbias[k] = 0.f;
      colbias[512 + k] = (1.f - g) * v_bias[k];
    }
  }
}

// ---------------- weight conversion fp32->bf16 -----------------------------
__global__ __launch_bounds__(256) void convw_kernel(
    const float* __restrict__ wq, const float* __restrict__ wk,
    const float* __restrict__ wv, const float* __restrict__ wp,
    u16* __restrict__ wb) {
  size_t i = ((size_t)blockIdx.x * 256 + threadIdx.x) * 4;
  constexpr size_t M4 = 4u * 1024 * 1024, M1 = 1024 * 1024;
  const float* src;
  if (i < M4) src = wq + i;
  else if (i < M4 + M1) src = wk + (i - M4);
  else if (i < M4 + 2 * M1) src = wv + (i - M4 - M1);
  else src = wp + (i - M4 - 2 * M1);
  float4 v = *(const float4*)src;
  ushort4 o;
  o.x = f2bf(v.x); o.y = f2bf(v.y); o.z = f2bf(v.z); o.w = f2bf(v.w);
  *(ushort4*)(wb + i) = o;
}

// ---------------- NT GEMM: C(MxN) = A(MxK) * B(NxK)^T, bf16 in, fp32 out ---
template <int BIAS, int SCALE>
__global__ __launch_bounds__(256) void gemm_nt(
    const u16* __restrict__ A, const u16* __restrict__ B, float* __restrict__ C,
    int M, int N, int K, const float* __restrict__ bias,
    const float* __restrict__ scale) {
  __shared__ u16 lA[128 * 32];
  __shared__ u16 lB[128 * 32];
  const int tid = threadIdx.x;
  const int lane = tid & 63, w = tid >> 6;
  const int m0 = blockIdx.y * 128, n0 = blockIdx.x * 128;
  const int mo = (w >> 1) * 64, no = (w & 1) * 64;
  const int r16 = lane & 15, q4 = lane >> 4;
  f32x4 acc[4][4] = {};

  for (int k0 = 0; k0 < K; k0 += 32) {
#pragma unroll
    for (int j = 0; j < 2; ++j) {
      int slot = j * 256 + tid;
      int row = slot >> 2, c8 = (slot & 3) * 8;
      gl_lds16(A + (size_t)(m0 + row) * K + k0 + c8, &lA[slot * 8]);
    }
#pragma unroll
    for (int j = 0; j < 2; ++j) {
      int slot = j * 256 + tid;
      int row = slot >> 2, c8 = (slot & 3) * 8;
      gl_lds16(B + (size_t)(n0 + row) * K + k0 + c8, &lB[slot * 8]);
    }
    __syncthreads();
    s16x8 af[4], bfr[4];
#pragma unroll
    for (int i = 0; i < 4; ++i)
      af[i] = *(const s16x8*)&lA[(mo + i * 16 + r16) * 32 + q4 * 8];
#pragma unroll
    for (int i = 0; i < 4; ++i)
      bfr[i] = *(const s16x8*)&lB[(no + i * 16 + r16) * 32 + q4 * 8];
#pragma unroll
    for (int mi = 0; mi < 4; ++mi)
#pragma unroll
      for (int ni = 0; ni < 4; ++ni)
        acc[mi][ni] = __builtin_amdgcn_mfma_f32_16x16x32_bf16(
            af[mi], bfr[ni], acc[mi][ni], 0, 0, 0);
    __syncthreads();
  }
  float sc = SCALE ? scale[0] : 1.0f;
#pragma unroll
  for (int mi = 0; mi < 4; ++mi) {
#pragma unroll
    for (int ni = 0; ni < 4; ++ni) {
      int col = n0 + no + ni * 16 + r16;
      float bv = BIAS ? bias[col] : 0.0f;
#pragma unroll
      for (int r = 0; r < 4; ++r) {
        int row = m0 + mo + mi * 16 + q4 * 4 + r;
        C[(size_t)row * N + col] = (acc[mi][ni][r] + bv) * sc;
      }
    }
  }
}

// ---------------- rmsnorm + rope for q and k -------------------------------
// q additionally scaled by gain^2 * (1/sqrt(128)) * log2(e) so flash softmax
// is pure exp2 with no per-score multiply.
__global__ __launch_bounds__(256) void postqk_kernel(
    const float* __restrict__ qraw, const float* __restrict__ kvraw,
    const float* __restrict__ qk_g, u16* __restrict__ qb,
    u16* __restrict__ kb) {
  constexpr int T = 2048;
  const int lane = threadIdx.x & 63, w = threadIdx.x >> 6;
  int p = blockIdx.x * 4 + w;  // 0..20*T-1
  const float* src;
  u16* dst;
  int t;
  float extra = 1.0f;
  if (p < 16 * T) {
    int hh = p >> 11; t = p & 2047;
    src = qraw + (size_t)t * 2048 + hh * 128;
    dst = qb + ((size_t)hh * T + t) * 128;
    float g = qk_g[hh];
    extra = g * g * 0.12751742f;  // 0.08838834765 * log2(e)
  } else {
    p -= 16 * T;
    int hh = p >> 11; t = p & 2047;
    src = kvraw + (size_t)t * 1024 + hh * 128;
    dst = kb + ((size_t)hh * T + t) * 128;
  }
  float x1 = src[lane], x2 = src[lane + 64];
  float ss = x1 * x1 + x2 * x2;
  ss += __shfl_xor(ss, 1);  ss += __shfl_xor(ss, 2);  ss += __shfl_xor(ss, 4);
  ss += __shfl_xor(ss, 8);  ss += __shfl_xor(ss, 16); ss += __shfl_xor(ss, 32);
  float rn = rsqrtf(ss * (1.0f / 128.0f) + 1.1920929e-7f) * extra;
  // inv_freq = 10000^(-lane/64) ; ln(10000)/64 = 0.14391156831212787
  float fr = (float)t * expf((float)lane * -0.14391156831212787f);
  float c = cosf(fr), s = sinf(fr);
  float y1 = (x1 * c + x2 * s) * rn;   // x1*cos + x2*sin
  float y2 = (x2 * c - x1 * s) * rn;   // -x1*sin + x2*cos
  dst[lane] = f2bf(y1);
  dst[lane + 64] = f2bf(y2);
}

// ---------------- transpose v: vT[hd][t] = kvraw[t][512+hd] ----------------
__global__ __launch_bounds__(256) void transv_kernel(
    const float* __restrict__ kvraw, u16* __restrict__ vT) {
  constexpr int T = 2048;
  __shared__ float tile[32][33];
  int t0 = blockIdx.x * 32, hd0 = blockIdx.y * 32;
  int tx = threadIdx.x & 31, ty = threadIdx.x >> 5;  // ty 0..7
#pragma unroll
  for (int i = 0; i < 4; ++i) {
    int t = t0 + ty + i * 8;
    tile[ty + i * 8][tx] = kvraw[(size_t)t * 1024 + 512 + hd0 + tx];
  }
  __syncthreads();
#pragma unroll
  for (int i = 0; i < 4; ++i) {
    int hd = hd0 + ty + i * 8;
    vT[(size_t)hd * T + t0 + tx] = f2bf(tile[tx][ty + i * 8]);
  }
}

// ---------------- causal GQA flash attention (v2) --------------------------
// grid: (32 qblocks reversed, 16 heads); 4 waves x 16 q-rows; KVBLK=64,
// double-buffered K/V staging with counted vmcnt + raw barriers (T3 2-phase).
__global__ __launch_bounds__(256) void flash_kernel(
    const u16* __restrict__ qb, const u16* __restrict__ kb,
    const u16* __restrict__ vT, u16* __restrict__ out) {
  constexpr int T = 2048;
  __shared__ u16 lK[2][64 * 128];  // [kv][d], byte ^= (row&7)<<4
  __shared__ u16 lV[2][128 * 64];  // [d][kv], byte ^= (row&7)<<4
  __shared__ u16 lP[4][16 * 72];   // per-wave P, stride 72 (2-way banks, free)
  const int tid = threadIdx.x, lane = tid & 63, w = tid >> 6;
  const int h = blockIdx.y, hkv = h >> 2;
  const int q0 = (int)(gridDim.x - 1 - blockIdx.x) * 64;
  const int r16 = lane & 15, q4 = lane >> 4;
  const int qrow = q0 + w * 16 + q4 * 4;  // + r

  // Q fragments (pre-scaled in postqk)
  s16x8 qf[4];
  {
    const u16* qp = qb + ((size_t)h * T + q0 + w * 16 + r16) * 128 + q4 * 8;
#pragma unroll
    for (int d = 0; d < 4; ++d) qf[d] = *(const s16x8*)(qp + d * 32);
  }

  // staging source offsets (per-thread constants)
  const u16* kbase = kb + (size_t)hkv * T * 128;
  const u16* vbase = vT + (size_t)hkv * 128 * T;
  int ks_off[4], vs_off[4];
#pragma unroll
  for (int j = 0; j < 4; ++j) {
    int slot = j * 256 + tid;
    int krow = slot >> 4, kc = slot & 15;
    int kcb = (kc * 16) ^ ((krow & 7) << 4);
    ks_off[j] = krow * 128 + (kcb >> 1);
    int vrow = slot >> 3, vc = slot & 7;
    int vcb = (vc * 16) ^ ((vrow & 7) << 4);
    vs_off[j] = vrow * T + (vcb >> 1);
  }

  f32x4 O[8] = {};
  float m_[4], l_[4];
#pragma unroll
  for (int r = 0; r < 4; ++r) { m_[r] = -3.0e38f; l_[r] = 0.f; }
  const int nt = q0 / 64 + 1;

  // prologue: stage tile 0 into buf 0
#pragma unroll
  for (int j = 0; j < 4; ++j)
    gl_lds16(kbase + ks_off[j], &lK[0][(j * 256 + tid) * 8]);
#pragma unroll
  for (int j = 0; j < 4; ++j)
    gl_lds16(vbase + vs_off[j], &lV[0][(j * 256 + tid) * 8]);
  asm volatile("s_waitcnt vmcnt(0)" ::: "memory");
  __builtin_amdgcn_s_barrier();

  for (int it = 0; it < nt; ++it) {
    const int t0 = it * 64;
    const int cur = it & 1;
    // stage next tile into the other buffer (overlaps with compute below)
    if (it + 1 < nt) {
      const int nxt = (it + 1) * 64;
#pragma unroll
      for (int j = 0; j < 4; ++j)
        gl_lds16(kbase + (size_t)nxt * 128 + ks_off[j],
                 &lK[cur ^ 1][(j * 256 + tid) * 8]);
#pragma unroll
      for (int j = 0; j < 4; ++j)
        gl_lds16(vbase + nxt + vs_off[j],
                 &lV[cur ^ 1][(j * 256 + tid) * 8]);
    }
    const u16* Kt = lK[cur];
    const u16* Vt = lV[cur];

    // ---- QK^T: 16 MFMA -> s[4] (kv halves of 16) ----
    f32x4 s[4];
#pragma unroll
    for (int kvh = 0; kvh < 4; ++kvh) {
      f32x4 acc = {};
#pragma unroll
      for (int d = 0; d < 4; ++d) {
        int cb = ((q4 * 16 + d * 64) ^ ((r16 & 7) << 4)) >> 1;
        acc = __builtin_amdgcn_mfma_f32_16x16x32_bf16(
            qf[d], *(const s16x8*)(Kt + (kvh * 16 + r16) * 128 + cb), acc, 0, 0, 0);
      }
      s[kvh] = acc;
    }

    // ---- causal mask: only tiles intersecting the wave's diagonal ----
    if (t0 + 64 > q0 + w * 16) {
#pragma unroll
      for (int kvh = 0; kvh < 4; ++kvh)
#pragma unroll
        for (int r = 0; r < 4; ++r)
          s[kvh][r] = (t0 + kvh * 16 + r16 <= qrow + r) ? s[kvh][r] : -1.0e30f;
    }

    // ---- online softmax (log2-space; Q pre-scaled by log2e*scale) ----
    float al[4];
#pragma unroll
    for (int r = 0; r < 4; ++r) {
      float t = fmaxf(fmaxf(s[0][r], s[1][r]), fmaxf(s[2][r], s[3][r]));
      t = fmaxf(t, __shfl_xor(t, 1));
      t = fmaxf(t, __shfl_xor(t, 2));
      t = fmaxf(t, __shfl_xor(t, 4));
      t = fmaxf(t, __shfl_xor(t, 8));
      float mn = fmaxf(m_[r], t);
      al[r] = __builtin_amdgcn_exp2f(m_[r] - mn);
      m_[r] = mn;
    }
    u16* myP = lP[w];
#pragma unroll
    for (int r = 0; r < 4; ++r) {
      float ps = 0.f;
      int prow = (q4 * 4 + r) * 72;
#pragma unroll
      for (int kvh = 0; kvh < 4; ++kvh) {
        float pp = __builtin_amdgcn_exp2f(s[kvh][r] - m_[r]);
        myP[prow + kvh * 16 + r16] = f2bf(pp);
        ps += pp;
      }
      ps += __shfl_xor(ps, 1); ps += __shfl_xor(ps, 2);
      ps += __shfl_xor(ps, 4); ps += __shfl_xor(ps, 8);
      l_[r] = l_[r] * al[r] + ps;
    }
#pragma unroll
    for (int dt = 0; dt < 8; ++dt)
#pragma unroll
      for (int r = 0; r < 4; ++r) O[dt][r] *= al[r];

    asm volatile("s_waitcnt lgkmcnt(0)" ::: "memory");
    __builtin_amdgcn_sched_barrier(0);
    s16x8 pf0 = *(const s16x8*)&myP[r16 * 72 + q4 * 8];
    s16x8 pf1 = *(const s16x8*)&myP[r16 * 72 + 32 + q4 * 8];

    // ---- PV: 16 MFMA ----
    int cb0 = ((q4 * 16) ^ ((r16 & 7) << 4)) >> 1;
    int cb1 = ((64 + q4 * 16) ^ ((r16 & 7) << 4)) >> 1;
#pragma unroll
    for (int dt = 0; dt < 8; ++dt) {
      const u16* vr = Vt + (dt * 16 + r16) * 64;
      O[dt] = __builtin_amdgcn_mfma_f32_16x16x32_bf16(
          pf0, *(const s16x8*)(vr + cb0), O[dt], 0, 0, 0);
      O[dt] = __builtin_amdgcn_mfma_f32_16x16x32_bf16(
          pf1, *(const s16x8*)(vr + cb1), O[dt], 0, 0, 0);
    }

    // next tile's loads have had the whole compute phase to land
    asm volatile("s_waitcnt vmcnt(0)" ::: "memory");
    __builtin_amdgcn_s_barrier();
  }

  float inv[4];
#pragma unroll
  for (int r = 0; r < 4; ++r) inv[r] = 1.0f / l_[r];
#pragma unroll
  for (int dt = 0; dt < 8; ++dt) {
#pragma unroll
    for (int r = 0; r < 4; ++r) {
      int row = qrow + r;
      int col = h * 128 + dt * 16 + r16;
      out[(size_t)row * 2048 + col] = f2bf(O[dt][r] * inv[r]);
    }
  }
}

// ---------------------------------------------------------------------------
extern "C" void kernel_launch(void* const* d_in, const int* in_sizes, int n_in,
                              void* d_out, int out_size, void* d_ws,
                              size_t ws_size, hipStream_t stream) {
  const float* x      = (const float*)d_in[0];
  const float* skip   = (const float*)d_in[1];
  const float* wq     = (const float*)d_in[2];
  const float* wk     = (const float*)d_in[3];
  const float* wv     = (const float*)d_in[4];
  const float* wp     = (const float*)d_in[5];
  const float* qk_g   = (const float*)d_in[6];
  const float* ln_s   = (const float*)d_in[7];
  const float* v_bias = (const float*)d_in[8];
  float* out = (float*)d_out;

  constexpr size_t MB = 1024 * 1024;
  char* ws = (char*)d_ws;
  u16*   wb    = (u16*)(ws);             // 10M bf16 = 20MB: wq|wk|wv|wp
  u16*   xb    = (u16*)(ws + 20 * MB);   // 8MB
  u16*   xmb   = (u16*)(ws + 28 * MB);   // 8MB
  float* qraw  = (float*)(ws + 36 * MB); // 16MB
  float* kvraw = (float*)(ws + 52 * MB); // 8MB
  u16*   qb    = (u16*)(ws + 60 * MB);   // 8MB
  u16*   kb    = (u16*)(ws + 68 * MB);   // 2MB
  u16*   vT    = (u16*)(ws + 70 * MB);   // 2MB
  u16*   ao    = (u16*)(ws + 72 * MB);   // 8MB
  float* colbias = (float*)(ws + 80 * MB);

  prep_kernel<<<4096, 256, 0, stream>>>(x, skip, ln_s, v_bias, xb, xmb,
                                        colbias);
  convw_kernel<<<10240, 256, 0, stream>>>(wq, wk, wv, wp, wb);
  gemm_nt<0, 0><<<dim3(16, 16), 256, 0, stream>>>(xb, wb, qraw, 2048, 2048,
                                                  2048, nullptr, nullptr);
  gemm_nt<1, 0><<<dim3(8, 16), 256, 0, stream>>>(
      xmb, wb + 4 * MB, kvraw, 2048, 1024, 2048, colbias, nullptr);
  postqk_kernel<<<10240, 256, 0, stream>>>(qraw, kvraw, qk_g, qb, kb);
  transv_kernel<<<dim3(64, 16), 256, 0, stream>>>(kvraw, vT);
  flash_kernel<<<dim3(32, 16), 256, 0, stream>>>(qb, kb, vT, ao);
  gemm_nt<0, 1><<<dim3(16, 16), 256, 0, stream>>>(
      ao, wb + 6 * MB, out, 2048, 2048, 2048, nullptr, ln_s);
}